// Round 12
// baseline (5782.500 us; speedup 1.0000x reference)
//
#include <hip/hip_runtime.h>
#include <cstdint>

#define B_ 32
#define L_ 512
#define G4_ 2048
#define POI 0xFFFFFFFFu

typedef __bf16          bf16x8 __attribute__((ext_vector_type(8)));
typedef float           f32x4  __attribute__((ext_vector_type(4)));
typedef unsigned short  u16x8  __attribute__((ext_vector_type(8)));
typedef unsigned int    u32x4  __attribute__((ext_vector_type(4)));

__device__ __forceinline__ unsigned short f2bf(float v) {
  unsigned int u = __float_as_uint(v);
  unsigned int r = u + 0x7fffu + ((u >> 16) & 1u);   // RNE
  return (unsigned short)(r >> 16);
}
__device__ __forceinline__ float bf2f(unsigned short u) {
  return __uint_as_float(((unsigned int)u) << 16);
}
__device__ __forceinline__ float sigf(float x) { return 1.0f / (1.0f + __expf(-x)); }
__device__ __forceinline__ float tanhf_(float x) { return 1.0f - 2.0f / (__expf(2.0f * x) + 1.0f); }

// ---------- sentinel (ws too small): d_out = 1.0 everywhere ----------
__global__ __launch_bounds__(256) void k_fill(float* o, long n, float v) {
  for (long i = (long)blockIdx.x * 256 + threadIdx.x; i < n; i += (long)gridDim.x * 256) o[i] = v;
}

// ---------- fp32 -> bf16 flat convert ----------
__global__ __launch_bounds__(256) void k_cvt(const float* __restrict__ in,
                                             unsigned short* __restrict__ out, long n) {
  long i = ((long)blockIdx.x * 256 + threadIdx.x) * 8;
  if (i >= n) return;
  const float4* p = (const float4*)(in + i);
  float4 a = p[0], b = p[1];
  u16x8 o;
  o[0] = f2bf(a.x); o[1] = f2bf(a.y); o[2] = f2bf(a.z); o[3] = f2bf(a.w);
  o[4] = f2bf(b.x); o[5] = f2bf(b.y); o[6] = f2bf(b.z); o[7] = f2bf(b.w);
  *(u16x8*)(out + i) = o;
}

// ---------- pack [w_ih | w_hh] -> wcat[2048][1024] bf16, gate-permuted ----------
__global__ __launch_bounds__(256) void k_pack_w(const float* __restrict__ wih,
                                                const float* __restrict__ whh,
                                                unsigned short* __restrict__ wcat) {
  long i = ((long)blockIdx.x * 256 + threadIdx.x) * 8;
  int nr = (int)(i >> 10), col = (int)(i & 1023);
  int cc = nr >> 7, wvp = (nr >> 4) & 7, OR = nr & 15;
  int grow = (OR & 3) * 512 + cc * 32 + wvp * 4 + (OR >> 2);
  const float* src = (col < 512) ? (wih + (long)grow * 512 + col)
                                 : (whh + (long)grow * 512 + (col - 512));
  const float4* p = (const float4*)src;
  float4 a = p[0], b = p[1];
  u16x8 o;
  o[0] = f2bf(a.x); o[1] = f2bf(a.y); o[2] = f2bf(a.z); o[3] = f2bf(a.w);
  o[4] = f2bf(b.x); o[5] = f2bf(b.y); o[6] = f2bf(b.z); o[7] = f2bf(b.w);
  *(u16x8*)(wcat + i) = o;
}

// ---------- persistent LSTM recurrence: single-barrier, single vmcnt pay-point ----------
// Per step: B -> 32 MFMAs -> gates -> store h(t) -> stage x(t+1) (alt buffer) ->
// issue x(t+2) prefetch -> issue h(t) poll -> vmcnt(0) (store-ack, prefetch and
// poll loads all CONCURRENT: pay max not sum) -> retry -> land h(t) -> B.
// Double-buffered LDS (64KB) so one barrier suffices; barrier drains nothing young.
struct LBias { const float* bi[3]; const float* bh[3]; };

__global__ __launch_bounds__(512, 1) void lstm_rec(
    const unsigned short* __restrict__ wcat,  // [3][2048][1024] gate-permuted
    const unsigned short* __restrict__ xs,    // [96][512][512]
    LBias bb,
    unsigned short* __restrict__ hout)        // [96][512][512], pre-poisoned
{
  const int r8 = blockIdx.x & 7;
  if (r8 >= 6) return;
  const int rg = r8, cc = blockIdx.x >> 3;
  const int l = rg >> 1, b0 = (rg & 1) * 16;
  const int tid = threadIdx.x, lane = tid & 63, wv = tid >> 6;

  __shared__ unsigned short sXH[2 * 16 * 1024];  // [2 bufs][16 seqs][x(512)|h(512)], XOR(row<<4)

  bf16x8 af[32];
  {
    int nr = cc * 128 + wv * 16 + (lane & 15);
    const unsigned short* Wp = wcat + ((long)l * G4_ + nr) * 1024 + ((lane >> 4) << 3);
#pragma unroll
    for (int kf = 0; kf < 32; ++kf) af[kf] = *(const bf16x8*)(Wp + kf * 32);
  }
  const int u = cc * 32 + wv * 4 + (lane >> 4);
  float bias[4];
#pragma unroll
  for (int r = 0; r < 4; ++r) bias[r] = bb.bi[l][r * 512 + u] + bb.bh[l][r * 512 + u];

  // staging geometry (within one 32KB buffer)
  const int sx = tid >> 5;                    // seq row 0..15
  const int slot = tid & 31;                  // 16B slot
  const int sw = sx << 4;
  const int xoff0 = sx * 2048 + slot * 16, xoff1 = xoff0 + 512;
  const int hoff0 = xoff0 + 1024,           hoff1 = hoff0 + 512;
  const int slot8 = slot * 8;
  const long seqbase = ((long)(l * B_ + b0 + sx)) * L_;

  // MFMA read geometry
  const int srow = lane & 15;
  const int rbm = srow << 11, swm = srow << 4;
  const int kob = (lane >> 4) << 4;

  // h-store geometry (lane-local gates)
  const int hseq = lane & 15;
  const long hrowb = ((long)(l * B_ + b0 + hseq)) * L_;
  const int upair = cc * 16 + wv * 2 + (lane >> 5);

  // prologue: stage x(0) into buf0 x-half, zero buf0 h-half, prefetch x(1)
  u32x4 xr0, xr1;
  {
    const unsigned short* p = xs + seqbase * 512 + slot8;
    u16x8 x0 = *(const u16x8*)p;
    u16x8 x1 = *(const u16x8*)(p + 256);
    *(u16x8*)((char*)sXH + (xoff0 ^ sw)) = x0;
    *(u16x8*)((char*)sXH + (xoff1 ^ sw)) = x1;
    u16x8 z = (u16x8){0, 0, 0, 0, 0, 0, 0, 0};
    *(u16x8*)((char*)sXH + (hoff0 ^ sw)) = z;
    *(u16x8*)((char*)sXH + (hoff1 ^ sw)) = z;
    const unsigned short* xp0 = xs + (seqbase + 1) * 512 + slot8;
    const unsigned short* xp1 = xp0 + 256;
    asm volatile("global_load_dwordx4 %0, %2, off\n\t"
                 "global_load_dwordx4 %1, %3, off"
                 : "=&v"(xr0), "=&v"(xr1) : "v"(xp0), "v"(xp1) : "memory");
  }
  float creg = 0.f;
  __syncthreads();                            // drains prologue prefetch (one-time)

  for (int t = 0; t < L_; ++t) {
    const int cbase = (t & 1) << 15;          // current buffer byte base
    const int nbase = cbase ^ (1 << 15);      // next buffer byte base

    // 32 MFMAs: x-half (kf 0..15) + h-half (kf 16..31), two acc chains
    f32x4 aA = (f32x4){0.f, 0.f, 0.f, 0.f};
    f32x4 aB = (f32x4){0.f, 0.f, 0.f, 0.f};
#pragma unroll
    for (int kf = 0; kf < 32; kf += 2) {
      bf16x8 bv0 = *(const bf16x8*)((const char*)sXH + (cbase + ((rbm + kf * 64 + kob) ^ swm)));
      bf16x8 bv1 = *(const bf16x8*)((const char*)sXH + (cbase + ((rbm + (kf + 1) * 64 + kob) ^ swm)));
      aA = __builtin_amdgcn_mfma_f32_16x16x32_bf16(af[kf], bv0, aA, 0, 0, 0);
      aB = __builtin_amdgcn_mfma_f32_16x16x32_bf16(af[kf + 1], bv1, aB, 0, 0, 0);
    }

    // gates -> h(t); store immediately (earliest possible)
    {
      float Pi = aA[0] + aB[0] + bias[0];
      float Pf = aA[1] + aB[1] + bias[1];
      float Pg = aA[2] + aB[2] + bias[2];
      float Po = aA[3] + aB[3] + bias[3];
      float iv = sigf(Pi), fv = sigf(Pf), gv = tanhf_(Pg), ov = sigf(Po);
      creg = fv * creg + iv * gv;
      float h = ov * tanhf_(creg);
      unsigned int hb16 = (unsigned int)f2bf(h);
      unsigned int other = (unsigned int)__shfl_xor((int)hb16, 16);
      if ((lane & 16) == 0) {
        unsigned int pk = hb16 | (other << 16);
        unsigned int* dst = (unsigned int*)(hout + (hrowb + t) * 512) + upair;
        __hip_atomic_store(dst, pk, __ATOMIC_RELAXED, __HIP_MEMORY_SCOPE_AGENT);
      }
    }

    if (t + 1 < L_) {
      // stage x(t+1) into next buffer (xr valid: last iter's vmcnt(0))
      *(u16x8*)((char*)sXH + (nbase + (xoff0 ^ sw))) = *(u16x8*)&xr0;
      *(u16x8*)((char*)sXH + (nbase + (xoff1 ^ sw))) = *(u16x8*)&xr1;
      // issue x(t+2) prefetch
      {
        int tn = (t + 2 < L_) ? t + 2 : t + 1;
        const unsigned short* xp0 = xs + (seqbase + tn) * 512 + slot8;
        const unsigned short* xp1 = xp0 + 256;
        asm volatile("global_load_dwordx4 %0, %2, off\n\t"
                     "global_load_dwordx4 %1, %3, off"
                     : "=&v"(xr0), "=&v"(xr1) : "v"(xp0), "v"(xp1) : "memory");
      }
      // issue h(t) poll loads; ONE vmcnt(0): store-ack + prefetch + poll concurrent
      u32x4 h0, h1;
      const unsigned short* hp0 = hout + (seqbase + t) * 512 + slot8;
      const unsigned short* hp1 = hp0 + 256;
      asm volatile("global_load_dwordx4 %0, %2, off sc1\n\t"
                   "global_load_dwordx4 %1, %3, off sc1\n\t"
                   "s_waitcnt vmcnt(0)"
                   : "=&v"(h0), "=&v"(h1) : "v"(hp0), "v"(hp1) : "memory");
      __builtin_amdgcn_sched_barrier(0);
      while (h0[0] == POI || h0[1] == POI || h0[2] == POI || h0[3] == POI ||
             h1[0] == POI || h1[1] == POI || h1[2] == POI || h1[3] == POI) {
        asm volatile("global_load_dwordx4 %0, %2, off sc1\n\t"
                     "global_load_dwordx4 %1, %3, off sc1\n\t"
                     "s_waitcnt vmcnt(0)"
                     : "=&v"(h0), "=&v"(h1) : "v"(hp0), "v"(hp1) : "memory");
        __builtin_amdgcn_sched_barrier(0);
      }
      // land h(t) into next buffer h-half
      *(u16x8*)((char*)sXH + (nbase + (hoff0 ^ sw))) = *(u16x8*)&h0;
      *(u16x8*)((char*)sXH + (nbase + (hoff1 ^ sw))) = *(u16x8*)&h1;
    }
    __syncthreads();                          // drains nothing young (all done at vmcnt)
  }
}

// ---------- fp32 flash attention (exact), bf16 in/out, parallel softmax ----------
__global__ __launch_bounds__(256) void attn_kernel(
    const unsigned short* __restrict__ h, unsigned short* __restrict__ attnout)
{
  const int qt = blockIdx.x, head = blockIdx.y, b = blockIdx.z;
  const int tid = threadIdx.x;

  __shared__ float q_lds[64 * 68];
  __shared__ float ks_lds[64 * 68];   // k tile, then reused for p values
  __shared__ float v_lds[64 * 68];

  const long qbase = ((long)b * L_) * 512;
  const long kbase = ((long)(B_ + b) * L_) * 512;
  const long vbase = ((long)(2 * B_ + b) * L_) * 512;

#pragma unroll
  for (int p = 0; p < 2; ++p) {
    int idx = p * 256 + tid;
    int row = idx >> 3, c8 = (idx & 7) << 3;
    u16x8 v8 = *(const u16x8*)(h + qbase + (long)(qt * 64 + row) * 512 + head * 64 + c8);
#pragma unroll
    for (int j = 0; j < 8; ++j) q_lds[row * 68 + c8 + j] = bf2f(v8[j]);
  }
  float m_run = -1e30f, lsum = 0.f;
  float acc[16];
#pragma unroll
  for (int j = 0; j < 16; ++j) acc[j] = 0.f;
  const int tq = tid & 15, tk = tid >> 4;
  const int oq = tid >> 2, od = (tid & 3) * 16;
  const int quad = tid & 3;

  for (int kt = 0; kt < 8; ++kt) {
    __syncthreads();
#pragma unroll
    for (int p = 0; p < 2; ++p) {
      int idx = p * 256 + tid;
      int row = idx >> 3, c8 = (idx & 7) << 3;
      u16x8 kv = *(const u16x8*)(h + kbase + (long)(kt * 64 + row) * 512 + head * 64 + c8);
      u16x8 vv = *(const u16x8*)(h + vbase + (long)(kt * 64 + row) * 512 + head * 64 + c8);
#pragma unroll
      for (int j = 0; j < 8; ++j) {
        ks_lds[row * 68 + c8 + j] = bf2f(kv[j]);
        v_lds[row * 68 + c8 + j]  = bf2f(vv[j]);
      }
    }
    __syncthreads();
    float sc[16];
#pragma unroll
    for (int x = 0; x < 16; ++x) sc[x] = 0.f;
    for (int d4 = 0; d4 < 64; d4 += 4) {
      f32x4 qv[4], kv4[4];
#pragma unroll
      for (int a = 0; a < 4; ++a) qv[a] = *(const f32x4*)&q_lds[(tq + a * 16) * 68 + d4];
#pragma unroll
      for (int c = 0; c < 4; ++c) kv4[c] = *(const f32x4*)&ks_lds[(tk + c * 16) * 68 + d4];
#pragma unroll
      for (int a = 0; a < 4; ++a)
#pragma unroll
        for (int c = 0; c < 4; ++c)
          sc[a * 4 + c] += qv[a][0] * kv4[c][0] + qv[a][1] * kv4[c][1] +
                           qv[a][2] * kv4[c][2] + qv[a][3] * kv4[c][3];
    }
    __syncthreads();
#pragma unroll
    for (int a = 0; a < 4; ++a)
#pragma unroll
      for (int c = 0; c < 4; ++c)
        ks_lds[(tq + a * 16) * 68 + (tk + c * 16)] = sc[a * 4 + c] * 0.125f;
    __syncthreads();
    // parallel online softmax: 4 threads per row (same mapping as PV: oq, quad)
    float corr;
    {
      float pv[16];
      float mx = m_run;
#pragma unroll
      for (int j = 0; j < 16; ++j) {
        pv[j] = ks_lds[oq * 68 + quad * 16 + j];
        mx = fmaxf(mx, pv[j]);
      }
      mx = fmaxf(mx, __shfl_xor(mx, 1));
      mx = fmaxf(mx, __shfl_xor(mx, 2));
      corr = __expf(m_run - mx);
      m_run = mx;
      float rs = 0.f;
#pragma unroll
      for (int j = 0; j < 16; ++j) {
        float p = __expf(pv[j] - mx);
        ks_lds[oq * 68 + quad * 16 + j] = p;
        rs += p;
      }
      rs += __shfl_xor(rs, 1);
      rs += __shfl_xor(rs, 2);
      lsum = lsum * corr + rs;
    }
    __syncthreads();
    {
#pragma unroll
      for (int j = 0; j < 16; ++j) acc[j] *= corr;
      for (int k = 0; k < 64; ++k) {
        float p = ks_lds[oq * 68 + k];
        f32x4 v0 = *(const f32x4*)&v_lds[k * 68 + od];
        f32x4 v1 = *(const f32x4*)&v_lds[k * 68 + od + 4];
        f32x4 v2 = *(const f32x4*)&v_lds[k * 68 + od + 8];
        f32x4 v3 = *(const f32x4*)&v_lds[k * 68 + od + 12];
#pragma unroll
        for (int j = 0; j < 4; ++j) {
          acc[j]      += p * v0[j];
          acc[4 + j]  += p * v1[j];
          acc[8 + j]  += p * v2[j];
          acc[12 + j] += p * v3[j];
        }
      }
    }
  }
  float inv = 1.0f / lsum;
  unsigned short* op = attnout + ((long)(b * L_ + qt * 64 + oq)) * 512 + head * 64 + od;
#pragma unroll
  for (int j = 0; j < 16; ++j) op[j] = f2bf(acc[j] * inv);
}

// ---------- projection GEMM: C[16384,512] = A[16384,512]·B[512,512]^T + bias ----------
__global__ __launch_bounds__(256) void gemm_proj(
    const unsigned short* __restrict__ A, const unsigned short* __restrict__ Bw,
    const float* __restrict__ bias, float* __restrict__ C)
{
  const int m0 = blockIdx.y * 128, n0 = blockIdx.x * 128;
  __shared__ unsigned short sA[128 * 64];
  __shared__ unsigned short sB[128 * 64];
  const int tid = threadIdx.x, lane = tid & 63, wv = tid >> 6;
  const int wr = wv >> 1, wc = wv & 1;
  f32x4 acc[4][4];
#pragma unroll
  for (int i = 0; i < 4; ++i)
#pragma unroll
    for (int j = 0; j < 4; ++j) acc[i][j] = (f32x4){0.f, 0.f, 0.f, 0.f};

  for (int kt = 0; kt < 512; kt += 64) {
#pragma unroll
    for (int p = 0; p < 4; ++p) {
      int g = p * 256 + tid;
      int r = g >> 3, c8 = (g & 7) << 3;
      int bo = ((r << 7) + (c8 << 1)) ^ ((r & 7) << 4);
      *(u16x8*)((char*)sA + bo) = *(const u16x8*)(A + (long)(m0 + r) * 512 + kt + c8);
      *(u16x8*)((char*)sB + bo) = *(const u16x8*)(Bw + (long)(n0 + r) * 512 + kt + c8);
    }
    __syncthreads();
#pragma unroll
    for (int kf = 0; kf < 2; ++kf) {
      int cb = kf * 32 + ((lane >> 4) << 3);
      bf16x8 av[4], bv[4];
#pragma unroll
      for (int i = 0; i < 4; ++i) {
        int ra = wr * 64 + i * 16 + (lane & 15);
        av[i] = *(const bf16x8*)((const char*)sA + (((ra << 7) + (cb << 1)) ^ ((ra & 7) << 4)));
        int rb = wc * 64 + i * 16 + (lane & 15);
        bv[i] = *(const bf16x8*)((const char*)sB + (((rb << 7) + (cb << 1)) ^ ((rb & 7) << 4)));
      }
#pragma unroll
      for (int i = 0; i < 4; ++i)
#pragma unroll
        for (int j = 0; j < 4; ++j)
          acc[i][j] = __builtin_amdgcn_mfma_f32_16x16x32_bf16(av[i], bv[j], acc[i][j], 0, 0, 0);
    }
    __syncthreads();
  }
#pragma unroll
  for (int i = 0; i < 4; ++i) {
    int gm0 = m0 + wr * 64 + i * 16 + ((lane >> 4) << 2);
#pragma unroll
    for (int j = 0; j < 4; ++j) {
      int gn = n0 + wc * 64 + j * 16 + (lane & 15);
      float bv = bias[gn];
#pragma unroll
      for (int r = 0; r < 4; ++r)
        C[(long)(gm0 + r) * 512 + gn] = acc[i][j][r] + bv;
    }
  }
}

// ---------- host ----------
extern "C" void kernel_launch(void* const* d_in, const int* in_sizes, int n_in,
                              void* d_out, int out_size, void* d_ws, size_t ws_size,
                              hipStream_t stream)
{
  const float* xin[3]  = {(const float*)d_in[0], (const float*)d_in[1], (const float*)d_in[2]};
  const float* w_ih[3] = {(const float*)d_in[3], (const float*)d_in[7],  (const float*)d_in[11]};
  const float* w_hh[3] = {(const float*)d_in[4], (const float*)d_in[8],  (const float*)d_in[12]};
  const float* b_ih[3] = {(const float*)d_in[5], (const float*)d_in[9],  (const float*)d_in[13]};
  const float* b_hh[3] = {(const float*)d_in[6], (const float*)d_in[10], (const float*)d_in[14]};
  const float* w_out = (const float*)d_in[15];
  const float* b_out = (const float*)d_in[16];

  const size_t TOTAL = 130547712ULL;
  if (ws_size < TOTAL) {
    k_fill<<<dim3(1024), dim3(256), 0, stream>>>((float*)d_out, (long)out_size, 1.0f);
    return;
  }
  char* ws = (char*)d_ws;
  unsigned short* xs      = (unsigned short*)(ws);
  unsigned short* hout    = (unsigned short*)(ws + 50331648);
  unsigned short* wcat    = (unsigned short*)(ws + 100663296);
  unsigned short* wouts   = (unsigned short*)(ws + 113246208);
  unsigned short* attnout = (unsigned short*)(ws + 113770496);

  // pre-poison hout (0xFF bytes = bf16 NaN pairs, unreachable as real h)
  hipMemsetAsync(hout, 0xFF, 50331648, stream);

  for (int l = 0; l < 3; ++l) {
    k_cvt<<<dim3(4096), dim3(256), 0, stream>>>(xin[l], xs + (long)l * 8388608, 8388608L);
    k_pack_w<<<dim3(1024), dim3(256), 0, stream>>>(w_ih[l], w_hh[l], wcat + (long)l * 2097152);
  }
  k_cvt<<<dim3(128), dim3(256), 0, stream>>>(w_out, wouts, 262144L);

  LBias bb;
  for (int l = 0; l < 3; ++l) { bb.bi[l] = b_ih[l]; bb.bh[l] = b_hh[l]; }
  lstm_rec<<<dim3(128), dim3(512), 0, stream>>>(wcat, xs, bb, hout);

  attn_kernel<<<dim3(8, 8, 32), dim3(256), 0, stream>>>(hout, attnout);

  gemm_proj<<<dim3(4, 128), dim3(256), 0, stream>>>(attnout, wouts, b_out, (float*)d_out);
}

// Round 13
// 1093.150 us; speedup vs baseline: 5.2898x; 5.2898x over previous
//
#include <hip/hip_runtime.h>
#include <cstdint>

#define B_ 32
#define L_ 512
#define G4_ 2048
#define POI 0xFFFFFFFFu

typedef __bf16          bf16x8 __attribute__((ext_vector_type(8)));
typedef float           f32x4  __attribute__((ext_vector_type(4)));
typedef unsigned short  u16x8  __attribute__((ext_vector_type(8)));
typedef unsigned int    u32x4  __attribute__((ext_vector_type(4)));

__device__ __forceinline__ unsigned short f2bf(float v) {
  unsigned int u = __float_as_uint(v);
  unsigned int r = u + 0x7fffu + ((u >> 16) & 1u);   // RNE
  return (unsigned short)(r >> 16);
}
__device__ __forceinline__ float bf2f(unsigned short u) {
  return __uint_as_float(((unsigned int)u) << 16);
}
__device__ __forceinline__ float sigf(float x) { return 1.0f / (1.0f + __expf(-x)); }
__device__ __forceinline__ float tanhf_(float x) { return 1.0f - 2.0f / (__expf(2.0f * x) + 1.0f); }

// ---------- sentinel (ws too small): d_out = 1.0 everywhere ----------
__global__ __launch_bounds__(256) void k_fill(float* o, long n, float v) {
  for (long i = (long)blockIdx.x * 256 + threadIdx.x; i < n; i += (long)gridDim.x * 256) o[i] = v;
}

// ---------- fp32 -> bf16 flat convert ----------
__global__ __launch_bounds__(256) void k_cvt(const float* __restrict__ in,
                                             unsigned short* __restrict__ out, long n) {
  long i = ((long)blockIdx.x * 256 + threadIdx.x) * 8;
  if (i >= n) return;
  const float4* p = (const float4*)(in + i);
  float4 a = p[0], b = p[1];
  u16x8 o;
  o[0] = f2bf(a.x); o[1] = f2bf(a.y); o[2] = f2bf(a.z); o[3] = f2bf(a.w);
  o[4] = f2bf(b.x); o[5] = f2bf(b.y); o[6] = f2bf(b.z); o[7] = f2bf(b.w);
  *(u16x8*)(out + i) = o;
}

// ---------- pack [w_ih | w_hh] -> wcat[2048][1024] bf16, gate-permuted ----------
// New row nr = cc*128 + wv*16 + OR, where OR&3 = gate, OR>>2 = unit_local(0..3):
// orig grow = (OR&3)*512 + cc*32 + wv*4 + (OR>>2).
// Each lane's MFMA acc[r] = gate r of ONE unit -> lane-local gate math.
__global__ __launch_bounds__(256) void k_pack_w(const float* __restrict__ wih,
                                                const float* __restrict__ whh,
                                                unsigned short* __restrict__ wcat) {
  long i = ((long)blockIdx.x * 256 + threadIdx.x) * 8;
  int nr = (int)(i >> 10), col = (int)(i & 1023);
  int cc = nr >> 7, wvp = (nr >> 4) & 7, OR = nr & 15;
  int grow = (OR & 3) * 512 + cc * 32 + wvp * 4 + (OR >> 2);
  const float* src = (col < 512) ? (wih + (long)grow * 512 + col)
                                 : (whh + (long)grow * 512 + (col - 512));
  const float4* p = (const float4*)src;
  float4 a = p[0], b = p[1];
  u16x8 o;
  o[0] = f2bf(a.x); o[1] = f2bf(a.y); o[2] = f2bf(a.z); o[3] = f2bf(a.w);
  o[4] = f2bf(b.x); o[5] = f2bf(b.y); o[6] = f2bf(b.z); o[7] = f2bf(b.w);
  *(u16x8*)(wcat + i) = o;
}

// ---------- persistent LSTM recurrence, fused Wx+Wh, poison-poll sync ----------
// r5/r9 configuration (verified 975us) — FROZEN. 96 blocks = 6 row-groups
// (16 seqs) x 16 col-chunks (32 units). Weights in registers (af[32] = 128
// VGPR). hout pre-poisoned 0xFFFFFFFF (bf16 NaN pair, unreachable: |h|<1).
// Producers fire-and-forget sc1 stores; consumers poll their own h words with
// sc1 dwordx4 loads until != poison. The barrier-A vmcnt drain doubles as
// store-visibility pacing (r7/r11/r12 reorders all regressed — do not touch).
struct LBias { const float* bi[3]; const float* bh[3]; };

__global__ __launch_bounds__(512, 1) void lstm_rec(
    const unsigned short* __restrict__ wcat,  // [3][2048][1024] gate-permuted
    const unsigned short* __restrict__ xs,    // [96][512][512]
    LBias bb,
    unsigned short* __restrict__ hout)        // [96][512][512], pre-poisoned
{
  const int r8 = blockIdx.x & 7;
  if (r8 >= 6) return;
  const int rg = r8, cc = blockIdx.x >> 3;
  const int l = rg >> 1, b0 = (rg & 1) * 16;
  const int tid = threadIdx.x, lane = tid & 63, wv = tid >> 6;

  __shared__ unsigned short sXH[16 * 1024];   // [16 seqs][x(512)|h(512)], XOR(row<<4)

  bf16x8 af[32];
  {
    int nr = cc * 128 + wv * 16 + (lane & 15);
    const unsigned short* Wp = wcat + ((long)l * G4_ + nr) * 1024 + ((lane >> 4) << 3);
#pragma unroll
    for (int kf = 0; kf < 32; ++kf) af[kf] = *(const bf16x8*)(Wp + kf * 32);
  }
  const int u = cc * 32 + wv * 4 + (lane >> 4);
  float bias[4];
#pragma unroll
  for (int r = 0; r < 4; ++r) bias[r] = bb.bi[l][r * 512 + u] + bb.bh[l][r * 512 + u];

  // staging geometry
  const int sx = tid >> 5;                    // seq row 0..15
  const int slot = tid & 31;                  // 16B slot
  const int sw = sx << 4;
  const int xoff0 = sx * 2048 + slot * 16, xoff1 = xoff0 + 512;
  const int hoff0 = xoff0 + 1024,           hoff1 = hoff0 + 512;
  const int slot8 = slot * 8;
  const long seqbase = ((long)(l * B_ + b0 + sx)) * L_;

  // MFMA read geometry
  const int srow = lane & 15;
  const int rbm = srow << 11, swm = srow << 4;
  const int kob = (lane >> 4) << 4;

  // h-store geometry (lane-local gates)
  const int hseq = lane & 15;
  const long hrowb = ((long)(l * B_ + b0 + hseq)) * L_;
  const int upair = cc * 16 + wv * 2 + (lane >> 5);

  u16x8 xr0, xr1;
  {
    const unsigned short* p = xs + seqbase * 512 + slot8;
    xr0 = *(const u16x8*)p;
    xr1 = *(const u16x8*)(p + 256);
  }
  float creg = 0.f;

  for (int t = 0; t < L_; ++t) {
    // stage x(t) into x-half
    *(u16x8*)((char*)sXH + (xoff0 ^ sw)) = xr0;
    *(u16x8*)((char*)sXH + (xoff1 ^ sw)) = xr1;
    if (t + 1 < L_) {
      const unsigned short* p = xs + (seqbase + t + 1) * 512 + slot8;
      xr0 = *(const u16x8*)p;
      xr1 = *(const u16x8*)(p + 256);
    }
    __syncthreads();                          // A: x staged

    // speculative h(t-1) loads (IF-direct), issued before x-MFMAs
    u32x4 h0 = (u32x4){0, 0, 0, 0}, h1 = (u32x4){0, 0, 0, 0};
    const unsigned short* hp0 = hout + (seqbase + t - 1) * 512 + slot8;
    const unsigned short* hp1 = hp0 + 256;
    if (t > 0) {
      asm volatile("global_load_dwordx4 %0, %2, off sc1\n\t"
                   "global_load_dwordx4 %1, %3, off sc1"
                   : "=&v"(h0), "=&v"(h1) : "v"(hp0), "v"(hp1) : "memory");
    }

    // x-half MFMAs (kf 0..15), two accumulator chains
    f32x4 aA = (f32x4){0.f, 0.f, 0.f, 0.f};
    f32x4 aB = (f32x4){0.f, 0.f, 0.f, 0.f};
#pragma unroll
    for (int kf = 0; kf < 16; kf += 2) {
      bf16x8 bv0 = *(const bf16x8*)((const char*)sXH + ((rbm + kf * 64 + kob) ^ swm));
      bf16x8 bv1 = *(const bf16x8*)((const char*)sXH + ((rbm + (kf + 1) * 64 + kob) ^ swm));
      aA = __builtin_amdgcn_mfma_f32_16x16x32_bf16(af[kf], bv0, aA, 0, 0, 0);
      aB = __builtin_amdgcn_mfma_f32_16x16x32_bf16(af[kf + 1], bv1, aB, 0, 0, 0);
    }

    // poison-poll: loop until all 8 words are real data
    if (t > 0) {
      asm volatile("s_waitcnt vmcnt(0)" ::: "memory");
      __builtin_amdgcn_sched_barrier(0);
      while (h0[0] == POI || h0[1] == POI || h0[2] == POI || h0[3] == POI ||
             h1[0] == POI || h1[1] == POI || h1[2] == POI || h1[3] == POI) {
        asm volatile("global_load_dwordx4 %0, %2, off sc1\n\t"
                     "global_load_dwordx4 %1, %3, off sc1\n\t"
                     "s_waitcnt vmcnt(0)"
                     : "=&v"(h0), "=&v"(h1) : "v"(hp0), "v"(hp1) : "memory");
        __builtin_amdgcn_sched_barrier(0);
      }
    }
    // land h into h-half
    *(u16x8*)((char*)sXH + (hoff0 ^ sw)) = *(u16x8*)&h0;
    *(u16x8*)((char*)sXH + (hoff1 ^ sw)) = *(u16x8*)&h1;
    __syncthreads();                          // B: h staged

    // h-half MFMAs (kf 16..31)
#pragma unroll
    for (int kf = 16; kf < 32; kf += 2) {
      bf16x8 bv0 = *(const bf16x8*)((const char*)sXH + ((rbm + kf * 64 + kob) ^ swm));
      bf16x8 bv1 = *(const bf16x8*)((const char*)sXH + ((rbm + (kf + 1) * 64 + kob) ^ swm));
      aA = __builtin_amdgcn_mfma_f32_16x16x32_bf16(af[kf], bv0, aA, 0, 0, 0);
      aB = __builtin_amdgcn_mfma_f32_16x16x32_bf16(af[kf + 1], bv1, aB, 0, 0, 0);
    }

    // lane-local gates; fire-and-forget h store (sc1 -> IF)
    {
      float Pi = aA[0] + aB[0] + bias[0];
      float Pf = aA[1] + aB[1] + bias[1];
      float Pg = aA[2] + aB[2] + bias[2];
      float Po = aA[3] + aB[3] + bias[3];
      float iv = sigf(Pi), fv = sigf(Pf), gv = tanhf_(Pg), ov = sigf(Po);
      creg = fv * creg + iv * gv;
      float h = ov * tanhf_(creg);
      unsigned int hb16 = (unsigned int)f2bf(h);
      unsigned int other = (unsigned int)__shfl_xor((int)hb16, 16);
      if ((lane & 16) == 0) {
        unsigned int pk = hb16 | (other << 16);
        unsigned int* dst = (unsigned int*)(hout + (hrowb + t) * 512) + upair;
        __hip_atomic_store(dst, pk, __ATOMIC_RELAXED, __HIP_MEMORY_SCOPE_AGENT);
      }
    }
  }
}

// ---------- MFMA flash attention: 4 waves x 16 q-rows, K-tile = 64 ----------
// Q/K/V already bf16 -> QK^T products identical to fp32 version (fp32 accum).
// V staged transposed so PV B-frags are contiguous b128. P rounded to bf16
// through a per-wave LDS patch (no cross-wave barrier). Online softmax is
// wave-local: row r lives in a 16-lane group -> shfl_xor(1,2,4,8) reduce.
__global__ __launch_bounds__(256) void attn_kernel(
    const unsigned short* __restrict__ h, unsigned short* __restrict__ attnout)
{
  const int qt = blockIdx.x, head = blockIdx.y, b = blockIdx.z;
  const int tid = threadIdx.x, lane = tid & 63, wv = tid >> 6;

  __shared__ unsigned short q_s[64 * 68];
  __shared__ unsigned short k_s[64 * 68];
  __shared__ unsigned short vt_s[64 * 68];    // vt_s[n*68+k] = V[k][n]
  __shared__ unsigned short p_s[4][16 * 72];  // per-wave P patch

  const long qbase = ((long)b * L_) * 512;
  const long kbase = ((long)(B_ + b) * L_) * 512;
  const long vbase = ((long)(2 * B_ + b) * L_) * 512;

  // stage Q (bf16 passthrough)
#pragma unroll
  for (int p = 0; p < 2; ++p) {
    int idx = p * 256 + tid;
    int row = idx >> 3, c8 = (idx & 7) << 3;
    *(u16x8*)&q_s[row * 68 + c8] =
        *(const u16x8*)(h + qbase + (long)(qt * 64 + row) * 512 + head * 64 + c8);
  }
  __syncthreads();
  // hoist per-wave Q fragments (A-frag: row = lane&15, k0 = (lane>>4)*8)
  const int k0 = (lane >> 4) << 3;
  bf16x8 qa0, qa1;
  {
    int m = wv * 16 + (lane & 15);
    qa0 = *(const bf16x8*)&q_s[m * 68 + k0];
    qa1 = *(const bf16x8*)&q_s[m * 68 + k0 + 32];
  }

  f32x4 O[4];
#pragma unroll
  for (int j = 0; j < 4; ++j) O[j] = (f32x4){0.f, 0.f, 0.f, 0.f};
  float m_run[4], lsum[4];
#pragma unroll
  for (int r = 0; r < 4; ++r) { m_run[r] = -1e30f; lsum[r] = 0.f; }

  for (int kt = 0; kt < 8; ++kt) {
    __syncthreads();                          // previous tile's k_s/vt_s reads done
#pragma unroll
    for (int p = 0; p < 2; ++p) {
      int idx = p * 256 + tid;
      int row = idx >> 3, c8 = (idx & 7) << 3;
      u16x8 kv = *(const u16x8*)(h + kbase + (long)(kt * 64 + row) * 512 + head * 64 + c8);
      u16x8 vv = *(const u16x8*)(h + vbase + (long)(kt * 64 + row) * 512 + head * 64 + c8);
      *(u16x8*)&k_s[row * 68 + c8] = kv;
#pragma unroll
      for (int j = 0; j < 8; ++j) vt_s[(c8 + j) * 68 + row] = vv[j];  // transpose scatter
    }
    __syncthreads();

    // S = Q·K^T (scaled): 4 n-tiles x 2 chained K=32 MFMAs
    f32x4 sc[4];
#pragma unroll
    for (int j = 0; j < 4; ++j) {
      int n = j * 16 + (lane & 15);
      bf16x8 kb0 = *(const bf16x8*)&k_s[n * 68 + k0];
      bf16x8 kb1 = *(const bf16x8*)&k_s[n * 68 + k0 + 32];
      f32x4 z = (f32x4){0.f, 0.f, 0.f, 0.f};
      z = __builtin_amdgcn_mfma_f32_16x16x32_bf16(qa0, kb0, z, 0, 0, 0);
      z = __builtin_amdgcn_mfma_f32_16x16x32_bf16(qa1, kb1, z, 0, 0, 0);
      sc[j] = z * 0.125f;
    }

    // online softmax (rows r: C-layout row=(lane>>4)*4+r; 16-lane group reduce)
    float corr[4];
#pragma unroll
    for (int r = 0; r < 4; ++r) {
      float mx = fmaxf(fmaxf(sc[0][r], sc[1][r]), fmaxf(sc[2][r], sc[3][r]));
      mx = fmaxf(mx, __shfl_xor(mx, 1));
      mx = fmaxf(mx, __shfl_xor(mx, 2));
      mx = fmaxf(mx, __shfl_xor(mx, 4));
      mx = fmaxf(mx, __shfl_xor(mx, 8));
      float mn = fmaxf(m_run[r], mx);
      corr[r] = __expf(m_run[r] - mn);
      m_run[r] = mn;
    }
    float rs[4] = {0.f, 0.f, 0.f, 0.f};
#pragma unroll
    for (int j = 0; j < 4; ++j)
#pragma unroll
      for (int r = 0; r < 4; ++r) {
        float pv = __expf(sc[j][r] - m_run[r]);
        rs[r] += pv;
        p_s[wv][((lane >> 4) * 4 + r) * 72 + j * 16 + (lane & 15)] = f2bf(pv);
      }
#pragma unroll
    for (int r = 0; r < 4; ++r) {
      float t = rs[r];
      t += __shfl_xor(t, 1);
      t += __shfl_xor(t, 2);
      t += __shfl_xor(t, 4);
      t += __shfl_xor(t, 8);
      lsum[r] = lsum[r] * corr[r] + t;
    }
#pragma unroll
    for (int j = 0; j < 4; ++j)
#pragma unroll
      for (int r = 0; r < 4; ++r) O[j][r] *= corr[r];

    // PV: read P A-frags (same-wave LDS dep; compiler inserts lgkmcnt)
    bf16x8 pa0 = *(const bf16x8*)&p_s[wv][(lane & 15) * 72 + k0];
    bf16x8 pa1 = *(const bf16x8*)&p_s[wv][(lane & 15) * 72 + k0 + 32];
#pragma unroll
    for (int j = 0; j < 4; ++j) {
      int n = j * 16 + (lane & 15);
      bf16x8 vb0 = *(const bf16x8*)&vt_s[n * 68 + k0];
      bf16x8 vb1 = *(const bf16x8*)&vt_s[n * 68 + k0 + 32];
      O[j] = __builtin_amdgcn_mfma_f32_16x16x32_bf16(pa0, vb0, O[j], 0, 0, 0);
      O[j] = __builtin_amdgcn_mfma_f32_16x16x32_bf16(pa1, vb1, O[j], 0, 0, 0);
    }
  }

  // epilogue: normalize, write bf16 (row=(lane>>4)*4+r, col=j*16+(lane&15))
  float inv[4];
#pragma unroll
  for (int r = 0; r < 4; ++r) inv[r] = 1.0f / lsum[r];
  const int orow0 = qt * 64 + wv * 16 + ((lane >> 4) << 2);
#pragma unroll
  for (int r = 0; r < 4; ++r) {
    unsigned short* op = attnout + ((long)(b * L_ + orow0 + r)) * 512 + head * 64 + (lane & 15);
#pragma unroll
    for (int j = 0; j < 4; ++j) op[j * 16] = f2bf(O[j][r] * inv[r]);
  }
}

// ---------- projection GEMM: C[16384,512] = A[16384,512]·B[512,512]^T + bias ----------
__global__ __launch_bounds__(256) void gemm_proj(
    const unsigned short* __restrict__ A, const unsigned short* __restrict__ Bw,
    const float* __restrict__ bias, float* __restrict__ C)
{
  const int m0 = blockIdx.y * 128, n0 = blockIdx.x * 128;
  __shared__ unsigned short sA[128 * 64];
  __shared__ unsigned short sB[128 * 64];
  const int tid = threadIdx.x, lane = tid & 63, wv = tid >> 6;
  const int wr = wv >> 1, wc = wv & 1;
  f32x4 acc[4][4];
#pragma unroll
  for (int i = 0; i < 4; ++i)
#pragma unroll
    for (int j = 0; j < 4; ++j) acc[i][j] = (f32x4){0.f, 0.f, 0.f, 0.f};

  for (int kt = 0; kt < 512; kt += 64) {
#pragma unroll
    for (int p = 0; p < 4; ++p) {
      int g = p * 256 + tid;
      int r = g >> 3, c8 = (g & 7) << 3;
      int bo = ((r << 7) + (c8 << 1)) ^ ((r & 7) << 4);
      *(u16x8*)((char*)sA + bo) = *(const u16x8*)(A + (long)(m0 + r) * 512 + kt + c8);
      *(u16x8*)((char*)sB + bo) = *(const u16x8*)(Bw + (long)(n0 + r) * 512 + kt + c8);
    }
    __syncthreads();
#pragma unroll
    for (int kf = 0; kf < 2; ++kf) {
      int cb = kf * 32 + ((lane >> 4) << 3);
      bf16x8 av[4], bv[4];
#pragma unroll
      for (int i = 0; i < 4; ++i) {
        int ra = wr * 64 + i * 16 + (lane & 15);
        av[i] = *(const bf16x8*)((const char*)sA + (((ra << 7) + (cb << 1)) ^ ((ra & 7) << 4)));
        int rb = wc * 64 + i * 16 + (lane & 15);
        bv[i] = *(const bf16x8*)((const char*)sB + (((rb << 7) + (cb << 1)) ^ ((rb & 7) << 4)));
      }
#pragma unroll
      for (int i = 0; i < 4; ++i)
#pragma unroll
        for (int j = 0; j < 4; ++j)
          acc[i][j] = __builtin_amdgcn_mfma_f32_16x16x32_bf16(av[i], bv[j], acc[i][j], 0, 0, 0);
    }
    __syncthreads();
  }
#pragma unroll
  for (int i = 0; i < 4; ++i) {
    int gm0 = m0 + wr * 64 + i * 16 + ((lane >> 4) << 2);
#pragma unroll
    for (int j = 0; j < 4; ++j) {
      int gn = n0 + wc * 64 + j * 16 + (lane & 15);
      float bv = bias[gn];
#pragma unroll
      for (int r = 0; r < 4; ++r)
        C[(long)(gm0 + r) * 512 + gn] = acc[i][j][r] + bv;
    }
  }
}

// ---------- host ----------
extern "C" void kernel_launch(void* const* d_in, const int* in_sizes, int n_in,
                              void* d_out, int out_size, void* d_ws, size_t ws_size,
                              hipStream_t stream)
{
  const float* xin[3]  = {(const float*)d_in[0], (const float*)d_in[1], (const float*)d_in[2]};
  const float* w_ih[3] = {(const float*)d_in[3], (const float*)d_in[7],  (const float*)d_in[11]};
  const float* w_hh[3] = {(const float*)d_in[4], (const float*)d_in[8],  (const float*)d_in[12]};
  const float* b_ih[3] = {(const float*)d_in[5], (const float*)d_in[9],  (const float*)d_in[13]};
  const float* b_hh[3] = {(const float*)d_in[6], (const float*)d_in[10], (const float*)d_in[14]};
  const float* w_out = (const float*)d_in[15];
  const float* b_out = (const float*)d_in[16];

  const size_t TOTAL = 130547712ULL;
  if (ws_size < TOTAL) {
    k_fill<<<dim3(1024), dim3(256), 0, stream>>>((float*)d_out, (long)out_size, 1.0f);
    return;
  }
  char* ws = (char*)d_ws;
  unsigned short* xs      = (unsigned short*)(ws);
  unsigned short* hout    = (unsigned short*)(ws + 50331648);
  unsigned short* wcat    = (unsigned short*)(ws + 100663296);
  unsigned short* wouts   = (unsigned short*)(ws + 113246208);
  unsigned short* attnout = (unsigned short*)(ws + 113770496);

  // pre-poison hout (0xFF bytes = bf16 NaN pairs, unreachable as real h)
  hipMemsetAsync(hout, 0xFF, 50331648, stream);

  for (int l = 0; l < 3; ++l) {
    k_cvt<<<dim3(4096), dim3(256), 0, stream>>>(xin[l], xs + (long)l * 8388608, 8388608L);
    k_pack_w<<<dim3(1024), dim3(256), 0, stream>>>(w_ih[l], w_hh[l], wcat + (long)l * 2097152);
  }
  k_cvt<<<dim3(128), dim3(256), 0, stream>>>(w_out, wouts, 262144L);

  LBias bb;
  for (int l = 0; l < 3; ++l) { bb.bi[l] = b_ih[l]; bb.bh[l] = b_hh[l]; }
  lstm_rec<<<dim3(128), dim3(512), 0, stream>>>(wcat, xs, bb, hout);

  attn_kernel<<<dim3(8, 8, 32), dim3(256), 0, stream>>>(hout, attnout);

  gemm_proj<<<dim3(4, 128), dim3(256), 0, stream>>>(attnout, wouts, b_out, (float*)d_out);
}

// Round 14
// 1081.419 us; speedup vs baseline: 5.3471x; 1.0108x over previous
//
#include <hip/hip_runtime.h>
#include <cstdint>

#define B_ 32
#define L_ 512
#define G4_ 2048
#define POI 0xFFFFFFFFu

typedef __bf16          bf16x8 __attribute__((ext_vector_type(8)));
typedef float           f32x4  __attribute__((ext_vector_type(4)));
typedef unsigned short  u16x8  __attribute__((ext_vector_type(8)));
typedef unsigned int    u32x4  __attribute__((ext_vector_type(4)));

__device__ __forceinline__ unsigned short f2bf(float v) {
  unsigned int u = __float_as_uint(v);
  unsigned int r = u + 0x7fffu + ((u >> 16) & 1u);   // RNE
  return (unsigned short)(r >> 16);
}
__device__ __forceinline__ float bf2f(unsigned short u) {
  return __uint_as_float(((unsigned int)u) << 16);
}
__device__ __forceinline__ float sigf(float x) { return 1.0f / (1.0f + __expf(-x)); }
__device__ __forceinline__ float tanhf_(float x) { return 1.0f - 2.0f / (__expf(2.0f * x) + 1.0f); }

// ---------- sentinel (ws too small): d_out = 1.0 everywhere ----------
__global__ __launch_bounds__(256) void k_fill(float* o, long n, float v) {
  for (long i = (long)blockIdx.x * 256 + threadIdx.x; i < n; i += (long)gridDim.x * 256) o[i] = v;
}

// ---------- fused preprocessing: x cvt x3 | weight pack x3 | wout cvt | hout poison ----------
// Unified task space (1 task = 8 u16 outputs = 16B). All segment sizes are
// powers of two -> shift/mask indexing, wave-uniform branches.
//   [0, 3*2^20)                x cvt:   xin[l] -> xs (bf16)
//   [NX, NX+3*2^18)            pack:    [w_ih|w_hh] -> wcat, gate-permuted
//   [.., +2^15)                wout cvt
//   [.., +3*2^20)              hout poison (0xFFFF bf16-NaN pairs)
// Poison via normal stores: kernel-end L2 writeback makes them visible to the
// sc1 poll loads (proven by 13 rounds of xs/wcat cross-kernel correctness).
struct PrepArgs {
  const float* xin[3];
  const float* wih[3];
  const float* whh[3];
  const float* wout;
  unsigned short* xs;     // [3][8388608]
  unsigned short* wcat;   // [3][2097152]
  unsigned short* wouts;  // [262144]
  unsigned short* hout;   // [25165824], poisoned
};

__device__ __forceinline__ u16x8 cvt8(const float* src) {
  const float4* p = (const float4*)src;
  float4 a = p[0], b = p[1];
  u16x8 o;
  o[0] = f2bf(a.x); o[1] = f2bf(a.y); o[2] = f2bf(a.z); o[3] = f2bf(a.w);
  o[4] = f2bf(b.x); o[5] = f2bf(b.y); o[6] = f2bf(b.z); o[7] = f2bf(b.w);
  return o;
}

__global__ __launch_bounds__(256) void k_prep(PrepArgs a) {
  const long NX = 3L << 20;            // 3,145,728
  const long NW = 3L << 18;            //   786,432
  const long NO = 1L << 15;            //    32,768
  const long NP = 3L << 20;            // 3,145,728
  const long T = NX + NW + NO + NP;
  for (long t = (long)blockIdx.x * 256 + threadIdx.x; t < T; t += (long)gridDim.x * 256) {
    if (t < NX) {
      int l = (int)(t >> 20);
      long i = (t & ((1L << 20) - 1)) << 3;
      *(u16x8*)(a.xs + (long)l * 8388608 + i) = cvt8(a.xin[l] + i);
    } else if (t < NX + NW) {
      long q = t - NX;
      int l = (int)(q >> 18);
      long i = (q & ((1L << 18) - 1)) << 3;
      int nr = (int)(i >> 10), col = (int)(i & 1023);
      int cc = nr >> 7, wvp = (nr >> 4) & 7, OR = nr & 15;
      int grow = (OR & 3) * 512 + cc * 32 + wvp * 4 + (OR >> 2);
      const float* src = (col < 512) ? (a.wih[l] + (long)grow * 512 + col)
                                     : (a.whh[l] + (long)grow * 512 + (col - 512));
      *(u16x8*)(a.wcat + (long)l * 2097152 + i) = cvt8(src);
    } else if (t < NX + NW + NO) {
      long i = (t - NX - NW) << 3;
      *(u16x8*)(a.wouts + i) = cvt8(a.wout + i);
    } else {
      long i = (t - NX - NW - NO) << 3;
      u16x8 pz;
#pragma unroll
      for (int j = 0; j < 8; ++j) pz[j] = 0xFFFFu;
      *(u16x8*)(a.hout + i) = pz;
    }
  }
}

// ---------- persistent LSTM recurrence, fused Wx+Wh, poison-poll sync ----------
// r5/r9 configuration (verified 975us) — FROZEN. 96 blocks = 6 row-groups
// (16 seqs) x 16 col-chunks (32 units). Weights in registers (af[32] = 128
// VGPR). hout pre-poisoned 0xFFFFFFFF (bf16 NaN pair, unreachable: |h|<1).
// Producers fire-and-forget sc1 stores; consumers poll their own h words with
// sc1 dwordx4 loads until != poison. The barrier-A vmcnt drain doubles as
// store-visibility pacing (r7/r11/r12 reorders all regressed — do not touch).
struct LBias { const float* bi[3]; const float* bh[3]; };

__global__ __launch_bounds__(512, 1) void lstm_rec(
    const unsigned short* __restrict__ wcat,  // [3][2048][1024] gate-permuted
    const unsigned short* __restrict__ xs,    // [96][512][512]
    LBias bb,
    unsigned short* __restrict__ hout)        // [96][512][512], pre-poisoned
{
  const int r8 = blockIdx.x & 7;
  if (r8 >= 6) return;
  const int rg = r8, cc = blockIdx.x >> 3;
  const int l = rg >> 1, b0 = (rg & 1) * 16;
  const int tid = threadIdx.x, lane = tid & 63, wv = tid >> 6;

  __shared__ unsigned short sXH[16 * 1024];   // [16 seqs][x(512)|h(512)], XOR(row<<4)

  bf16x8 af[32];
  {
    int nr = cc * 128 + wv * 16 + (lane & 15);
    const unsigned short* Wp = wcat + ((long)l * G4_ + nr) * 1024 + ((lane >> 4) << 3);
#pragma unroll
    for (int kf = 0; kf < 32; ++kf) af[kf] = *(const bf16x8*)(Wp + kf * 32);
  }
  const int u = cc * 32 + wv * 4 + (lane >> 4);
  float bias[4];
#pragma unroll
  for (int r = 0; r < 4; ++r) bias[r] = bb.bi[l][r * 512 + u] + bb.bh[l][r * 512 + u];

  // staging geometry
  const int sx = tid >> 5;                    // seq row 0..15
  const int slot = tid & 31;                  // 16B slot
  const int sw = sx << 4;
  const int xoff0 = sx * 2048 + slot * 16, xoff1 = xoff0 + 512;
  const int hoff0 = xoff0 + 1024,           hoff1 = hoff0 + 512;
  const int slot8 = slot * 8;
  const long seqbase = ((long)(l * B_ + b0 + sx)) * L_;

  // MFMA read geometry
  const int srow = lane & 15;
  const int rbm = srow << 11, swm = srow << 4;
  const int kob = (lane >> 4) << 4;

  // h-store geometry (lane-local gates)
  const int hseq = lane & 15;
  const long hrowb = ((long)(l * B_ + b0 + hseq)) * L_;
  const int upair = cc * 16 + wv * 2 + (lane >> 5);

  u16x8 xr0, xr1;
  {
    const unsigned short* p = xs + seqbase * 512 + slot8;
    xr0 = *(const u16x8*)p;
    xr1 = *(const u16x8*)(p + 256);
  }
  float creg = 0.f;

  for (int t = 0; t < L_; ++t) {
    // stage x(t) into x-half
    *(u16x8*)((char*)sXH + (xoff0 ^ sw)) = xr0;
    *(u16x8*)((char*)sXH + (xoff1 ^ sw)) = xr1;
    if (t + 1 < L_) {
      const unsigned short* p = xs + (seqbase + t + 1) * 512 + slot8;
      xr0 = *(const u16x8*)p;
      xr1 = *(const u16x8*)(p + 256);
    }
    __syncthreads();                          // A: x staged

    // speculative h(t-1) loads (IF-direct), issued before x-MFMAs
    u32x4 h0 = (u32x4){0, 0, 0, 0}, h1 = (u32x4){0, 0, 0, 0};
    const unsigned short* hp0 = hout + (seqbase + t - 1) * 512 + slot8;
    const unsigned short* hp1 = hp0 + 256;
    if (t > 0) {
      asm volatile("global_load_dwordx4 %0, %2, off sc1\n\t"
                   "global_load_dwordx4 %1, %3, off sc1"
                   : "=&v"(h0), "=&v"(h1) : "v"(hp0), "v"(hp1) : "memory");
    }

    // x-half MFMAs (kf 0..15), two accumulator chains
    f32x4 aA = (f32x4){0.f, 0.f, 0.f, 0.f};
    f32x4 aB = (f32x4){0.f, 0.f, 0.f, 0.f};
#pragma unroll
    for (int kf = 0; kf < 16; kf += 2) {
      bf16x8 bv0 = *(const bf16x8*)((const char*)sXH + ((rbm + kf * 64 + kob) ^ swm));
      bf16x8 bv1 = *(const bf16x8*)((const char*)sXH + ((rbm + (kf + 1) * 64 + kob) ^ swm));
      aA = __builtin_amdgcn_mfma_f32_16x16x32_bf16(af[kf], bv0, aA, 0, 0, 0);
      aB = __builtin_amdgcn_mfma_f32_16x16x32_bf16(af[kf + 1], bv1, aB, 0, 0, 0);
    }

    // poison-poll: loop until all 8 words are real data
    if (t > 0) {
      asm volatile("s_waitcnt vmcnt(0)" ::: "memory");
      __builtin_amdgcn_sched_barrier(0);
      while (h0[0] == POI || h0[1] == POI || h0[2] == POI || h0[3] == POI ||
             h1[0] == POI || h1[1] == POI || h1[2] == POI || h1[3] == POI) {
        asm volatile("global_load_dwordx4 %0, %2, off sc1\n\t"
                     "global_load_dwordx4 %1, %3, off sc1\n\t"
                     "s_waitcnt vmcnt(0)"
                     : "=&v"(h0), "=&v"(h1) : "v"(hp0), "v"(hp1) : "memory");
        __builtin_amdgcn_sched_barrier(0);
      }
    }
    // land h into h-half
    *(u16x8*)((char*)sXH + (hoff0 ^ sw)) = *(u16x8*)&h0;
    *(u16x8*)((char*)sXH + (hoff1 ^ sw)) = *(u16x8*)&h1;
    __syncthreads();                          // B: h staged

    // h-half MFMAs (kf 16..31)
#pragma unroll
    for (int kf = 16; kf < 32; kf += 2) {
      bf16x8 bv0 = *(const bf16x8*)((const char*)sXH + ((rbm + kf * 64 + kob) ^ swm));
      bf16x8 bv1 = *(const bf16x8*)((const char*)sXH + ((rbm + (kf + 1) * 64 + kob) ^ swm));
      aA = __builtin_amdgcn_mfma_f32_16x16x32_bf16(af[kf], bv0, aA, 0, 0, 0);
      aB = __builtin_amdgcn_mfma_f32_16x16x32_bf16(af[kf + 1], bv1, aB, 0, 0, 0);
    }

    // lane-local gates; fire-and-forget h store (sc1 -> IF)
    {
      float Pi = aA[0] + aB[0] + bias[0];
      float Pf = aA[1] + aB[1] + bias[1];
      float Pg = aA[2] + aB[2] + bias[2];
      float Po = aA[3] + aB[3] + bias[3];
      float iv = sigf(Pi), fv = sigf(Pf), gv = tanhf_(Pg), ov = sigf(Po);
      creg = fv * creg + iv * gv;
      float h = ov * tanhf_(creg);
      unsigned int hb16 = (unsigned int)f2bf(h);
      unsigned int other = (unsigned int)__shfl_xor((int)hb16, 16);
      if ((lane & 16) == 0) {
        unsigned int pk = hb16 | (other << 16);
        unsigned int* dst = (unsigned int*)(hout + (hrowb + t) * 512) + upair;
        __hip_atomic_store(dst, pk, __ATOMIC_RELAXED, __HIP_MEMORY_SCOPE_AGENT);
      }
    }
  }
}

// ---------- MFMA flash attention: 4 waves x 16 q-rows, K-tile = 64 ----------
__global__ __launch_bounds__(256) void attn_kernel(
    const unsigned short* __restrict__ h, unsigned short* __restrict__ attnout)
{
  const int qt = blockIdx.x, head = blockIdx.y, b = blockIdx.z;
  const int tid = threadIdx.x, lane = tid & 63, wv = tid >> 6;

  __shared__ unsigned short q_s[64 * 68];
  __shared__ unsigned short k_s[64 * 68];
  __shared__ unsigned short vt_s[64 * 68];    // vt_s[n*68+k] = V[k][n]
  __shared__ unsigned short p_s[4][16 * 72];  // per-wave P patch

  const long qbase = ((long)b * L_) * 512;
  const long kbase = ((long)(B_ + b) * L_) * 512;
  const long vbase = ((long)(2 * B_ + b) * L_) * 512;

#pragma unroll
  for (int p = 0; p < 2; ++p) {
    int idx = p * 256 + tid;
    int row = idx >> 3, c8 = (idx & 7) << 3;
    *(u16x8*)&q_s[row * 68 + c8] =
        *(const u16x8*)(h + qbase + (long)(qt * 64 + row) * 512 + head * 64 + c8);
  }
  __syncthreads();
  const int k0 = (lane >> 4) << 3;
  bf16x8 qa0, qa1;
  {
    int m = wv * 16 + (lane & 15);
    qa0 = *(const bf16x8*)&q_s[m * 68 + k0];
    qa1 = *(const bf16x8*)&q_s[m * 68 + k0 + 32];
  }

  f32x4 O[4];
#pragma unroll
  for (int j = 0; j < 4; ++j) O[j] = (f32x4){0.f, 0.f, 0.f, 0.f};
  float m_run[4], lsum[4];
#pragma unroll
  for (int r = 0; r < 4; ++r) { m_run[r] = -1e30f; lsum[r] = 0.f; }

  for (int kt = 0; kt < 8; ++kt) {
    __syncthreads();
#pragma unroll
    for (int p = 0; p < 2; ++p) {
      int idx = p * 256 + tid;
      int row = idx >> 3, c8 = (idx & 7) << 3;
      u16x8 kv = *(const u16x8*)(h + kbase + (long)(kt * 64 + row) * 512 + head * 64 + c8);
      u16x8 vv = *(const u16x8*)(h + vbase + (long)(kt * 64 + row) * 512 + head * 64 + c8);
      *(u16x8*)&k_s[row * 68 + c8] = kv;
#pragma unroll
      for (int j = 0; j < 8; ++j) vt_s[(c8 + j) * 68 + row] = vv[j];
    }
    __syncthreads();

    f32x4 sc[4];
#pragma unroll
    for (int j = 0; j < 4; ++j) {
      int n = j * 16 + (lane & 15);
      bf16x8 kb0 = *(const bf16x8*)&k_s[n * 68 + k0];
      bf16x8 kb1 = *(const bf16x8*)&k_s[n * 68 + k0 + 32];
      f32x4 z = (f32x4){0.f, 0.f, 0.f, 0.f};
      z = __builtin_amdgcn_mfma_f32_16x16x32_bf16(qa0, kb0, z, 0, 0, 0);
      z = __builtin_amdgcn_mfma_f32_16x16x32_bf16(qa1, kb1, z, 0, 0, 0);
      sc[j] = z * 0.125f;
    }

    float corr[4];
#pragma unroll
    for (int r = 0; r < 4; ++r) {
      float mx = fmaxf(fmaxf(sc[0][r], sc[1][r]), fmaxf(sc[2][r], sc[3][r]));
      mx = fmaxf(mx, __shfl_xor(mx, 1));
      mx = fmaxf(mx, __shfl_xor(mx, 2));
      mx = fmaxf(mx, __shfl_xor(mx, 4));
      mx = fmaxf(mx, __shfl_xor(mx, 8));
      float mn = fmaxf(m_run[r], mx);
      corr[r] = __expf(m_run[r] - mn);
      m_run[r] = mn;
    }
    float rs[4] = {0.f, 0.f, 0.f, 0.f};
#pragma unroll
    for (int j = 0; j < 4; ++j)
#pragma unroll
      for (int r = 0; r < 4; ++r) {
        float pv = __expf(sc[j][r] - m_run[r]);
        rs[r] += pv;
        p_s[wv][((lane >> 4) * 4 + r) * 72 + j * 16 + (lane & 15)] = f2bf(pv);
      }
#pragma unroll
    for (int r = 0; r < 4; ++r) {
      float t = rs[r];
      t += __shfl_xor(t, 1);
      t += __shfl_xor(t, 2);
      t += __shfl_xor(t, 4);
      t += __shfl_xor(t, 8);
      lsum[r] = lsum[r] * corr[r] + t;
    }
#pragma unroll
    for (int j = 0; j < 4; ++j)
#pragma unroll
      for (int r = 0; r < 4; ++r) O[j][r] *= corr[r];

    bf16x8 pa0 = *(const bf16x8*)&p_s[wv][(lane & 15) * 72 + k0];
    bf16x8 pa1 = *(const bf16x8*)&p_s[wv][(lane & 15) * 72 + k0 + 32];
#pragma unroll
    for (int j = 0; j < 4; ++j) {
      int n = j * 16 + (lane & 15);
      bf16x8 vb0 = *(const bf16x8*)&vt_s[n * 68 + k0];
      bf16x8 vb1 = *(const bf16x8*)&vt_s[n * 68 + k0 + 32];
      O[j] = __builtin_amdgcn_mfma_f32_16x16x32_bf16(pa0, vb0, O[j], 0, 0, 0);
      O[j] = __builtin_amdgcn_mfma_f32_16x16x32_bf16(pa1, vb1, O[j], 0, 0, 0);
    }
  }

  float inv[4];
#pragma unroll
  for (int r = 0; r < 4; ++r) inv[r] = 1.0f / lsum[r];
  const int orow0 = qt * 64 + wv * 16 + ((lane >> 4) << 2);
#pragma unroll
  for (int r = 0; r < 4; ++r) {
    unsigned short* op = attnout + ((long)(b * L_ + orow0 + r)) * 512 + head * 64 + (lane & 15);
#pragma unroll
    for (int j = 0; j < 4; ++j) op[j * 16] = f2bf(O[j][r] * inv[r]);
  }
}

// ---------- projection GEMM: C[16384,512] = A[16384,512]·B[512,512]^T + bias ----------
__global__ __launch_bounds__(256) void gemm_proj(
    const unsigned short* __restrict__ A, const unsigned short* __restrict__ Bw,
    const float* __restrict__ bias, float* __restrict__ C)
{
  const int m0 = blockIdx.y * 128, n0 = blockIdx.x * 128;
  __shared__ unsigned short sA[128 * 64];
  __shared__ unsigned short sB[128 * 64];
  const int tid = threadIdx.x, lane = tid & 63, wv = tid >> 6;
  const int wr = wv >> 1, wc = wv & 1;
  f32x4 acc[4][4];
#pragma unroll
  for (int i = 0; i < 4; ++i)
#pragma unroll
    for (int j = 0; j < 4; ++j) acc[i][j] = (f32x4){0.f, 0.f, 0.f, 0.f};

  for (int kt = 0; kt < 512; kt += 64) {
#pragma unroll
    for (int p = 0; p < 4; ++p) {
      int g = p * 256 + tid;
      int r = g >> 3, c8 = (g & 7) << 3;
      int bo = ((r << 7) + (c8 << 1)) ^ ((r & 7) << 4);
      *(u16x8*)((char*)sA + bo) = *(const u16x8*)(A + (long)(m0 + r) * 512 + kt + c8);
      *(u16x8*)((char*)sB + bo) = *(const u16x8*)(Bw + (long)(n0 + r) * 512 + kt + c8);
    }
    __syncthreads();
#pragma unroll
    for (int kf = 0; kf < 2; ++kf) {
      int cb = kf * 32 + ((lane >> 4) << 3);
      bf16x8 av[4], bv[4];
#pragma unroll
      for (int i = 0; i < 4; ++i) {
        int ra = wr * 64 + i * 16 + (lane & 15);
        av[i] = *(const bf16x8*)((const char*)sA + (((ra << 7) + (cb << 1)) ^ ((ra & 7) << 4)));
        int rb = wc * 64 + i * 16 + (lane & 15);
        bv[i] = *(const bf16x8*)((const char*)sB + (((rb << 7) + (cb << 1)) ^ ((rb & 7) << 4)));
      }
#pragma unroll
      for (int i = 0; i < 4; ++i)
#pragma unroll
        for (int j = 0; j < 4; ++j)
          acc[i][j] = __builtin_amdgcn_mfma_f32_16x16x32_bf16(av[i], bv[j], acc[i][j], 0, 0, 0);
    }
    __syncthreads();
  }
#pragma unroll
  for (int i = 0; i < 4; ++i) {
    int gm0 = m0 + wr * 64 + i * 16 + ((lane >> 4) << 2);
#pragma unroll
    for (int j = 0; j < 4; ++j) {
      int gn = n0 + wc * 64 + j * 16 + (lane & 15);
      float bv = bias[gn];
#pragma unroll
      for (int r = 0; r < 4; ++r)
        C[(long)(gm0 + r) * 512 + gn] = acc[i][j][r] + bv;
    }
  }
}

// ---------- host ----------
extern "C" void kernel_launch(void* const* d_in, const int* in_sizes, int n_in,
                              void* d_out, int out_size, void* d_ws, size_t ws_size,
                              hipStream_t stream)
{
  const float* xin[3]  = {(const float*)d_in[0], (const float*)d_in[1], (const float*)d_in[2]};
  const float* w_ih[3] = {(const float*)d_in[3], (const float*)d_in[7],  (const float*)d_in[11]};
  const float* w_hh[3] = {(const float*)d_in[4], (const float*)d_in[8],  (const float*)d_in[12]};
  const float* b_ih[3] = {(const float*)d_in[5], (const float*)d_in[9],  (const float*)d_in[13]};
  const float* b_hh[3] = {(const float*)d_in[6], (const float*)d_in[10], (const float*)d_in[14]};
  const float* w_out = (const float*)d_in[15];
  const float* b_out = (const float*)d_in[16];

  const size_t TOTAL = 130547712ULL;
  if (ws_size < TOTAL) {
    k_fill<<<dim3(1024), dim3(256), 0, stream>>>((float*)d_out, (long)out_size, 1.0f);
    return;
  }
  char* ws = (char*)d_ws;
  unsigned short* xs      = (unsigned short*)(ws);
  unsigned short* hout    = (unsigned short*)(ws + 50331648);
  unsigned short* wcat    = (unsigned short*)(ws + 100663296);
  unsigned short* wouts   = (unsigned short*)(ws + 113246208);
  unsigned short* attnout = (unsigned short*)(ws + 113770496);

  // fused prep: cvt + pack + wout + hout poison in ONE dispatch
  PrepArgs pa;
  for (int l = 0; l < 3; ++l) { pa.xin[l] = xin[l]; pa.wih[l] = w_ih[l]; pa.whh[l] = w_hh[l]; }
  pa.wout = w_out;
  pa.xs = xs; pa.wcat = wcat; pa.wouts = wouts; pa.hout = hout;
  k_prep<<<dim3(2048), dim3(256), 0, stream>>>(pa);

  LBias bb;
  for (int l = 0; l < 3; ++l) { bb.bi[l] = b_ih[l]; bb.bh[l] = b_hh[l]; }
  lstm_rec<<<dim3(128), dim3(512), 0, stream>>>(wcat, xs, bb, hout);

  attn_kernel<<<dim3(8, 8, 32), dim3(256), 0, stream>>>(hout, attnout);

  gemm_proj<<<dim3(4, 128), dim3(256), 0, stream>>>(attnout, wouts, b_out, (float*)d_out);
}